// Round 11
// baseline (189.822 us; speedup 1.0000x reference)
//
#include <hip/hip_runtime.h>
#include <math.h>

#define HIDDEN 128
#define NGRAPH 16384
#define GPB 32                  // graphs per block
#define NBLK (NGRAPH / GPB)     // 512 blocks
#define NTHR 512                // 8 waves/block; 2 blocks/CU = 16 waves/CU

typedef __attribute__((ext_vector_type(8))) short short8;   // 8 bf16
typedef __attribute__((ext_vector_type(4))) float f32x4;    // MFMA accum

// shifted-softplus shift = log(2)
__device__ __constant__ float kSHIFT = 0.69314718055994530942f;

// fp32 -> bf16 (RNE), bit-level
__device__ __forceinline__ unsigned short f2bf(float f) {
    unsigned int u = __builtin_bit_cast(unsigned int, f);
    u = (u + 0x7FFFu + ((u >> 16) & 1u)) >> 16;
    return (unsigned short)u;
}

// ---------------------------------------------------------------------------
// Kernel 0: boundary scan. batch sorted; thread i writes offs[g]=i for every
// graph g starting at i (covers empty graphs). offs[NGRAPH]=n_nodes.
// ---------------------------------------------------------------------------
__global__ __launch_bounds__(256) void offsets_kernel(
    const int* __restrict__ batch, int* __restrict__ offs, int n_nodes)
{
    int i = blockIdx.x * blockDim.x + threadIdx.x;
    if (i >= n_nodes) return;
    int b = batch[i];
    int prev = (i == 0) ? -1 : batch[i - 1];
    for (int g = prev + 1; g <= b; ++g) offs[g] = i;        // rare
    if (i == n_nodes - 1)
        for (int g = b + 1; g <= NGRAPH; ++g) offs[g] = n_nodes;
}

// ---------------------------------------------------------------------------
// Fused kernel: 512 blocks x 512 threads (8 waves), 32 graphs/block.
// Phase 1 (BLOCK-INTERLEAVED STREAM): the whole block sweeps its row range
//   [offs[g0], offs[g0+32]) together in 64-row steps. Thread t covers the
//   float4 quad (t&31) of rows base + i*16 + (t>>5), i=0..3 (4 loads in
//   flight). The block's memory trace is 32-KB SEQUENTIAL bursts -> 512
//   ordered DRAM streams chip-wide instead of 4096 private wave streams
//   (hypothesis: recovers row-buffer locality, ~+20% effective BW).
//   Per-thread register run-accumulation; on graph-boundary crossing, flush
//   the run into the fp32 LDS accumulator with 4x atomicAdd (ds_add_f32).
// Convert: u_s fp32 -> u_b bf16, XOR-swizzled rows (one tiny pass).
// Phase 2 (unchanged from R8/R10): W1 B-frags in registers, 16 x
//   v_mfma_f32_16x16x32_bf16 per wave, swizzled conflict-free ds_read_b128
//   A-frags. Epilogue: bias -> shifted softplus -> *W2 -> 16-lane shfl
//   reduce -> cross-wave LDS reduce.
// LDS: 16 KB u_s + 8 KB u_b + 1 KB red + offs = ~25.2 KB -> 2 blocks/CU.
// ---------------------------------------------------------------------------
__global__ __launch_bounds__(NTHR, 4) void fused_kernel(
    const float* __restrict__ v, const int* __restrict__ offs,
    const float* __restrict__ W1, const float* __restrict__ b1,
    const float* __restrict__ W2, const float* __restrict__ b2,
    float* __restrict__ out)
{
    __shared__ float u_s[GPB * HIDDEN];    // 16 KB fp32 accumulator
    __shared__ short u_b[GPB * HIDDEN];    // 8 KB bf16, k XOR-swizzled per row
    __shared__ float red_s[8][GPB];        // 1 KB
    __shared__ int   offs_s[GPB + 1];

    const int t  = threadIdx.x;
    const int l  = t & 63;
    const int w  = t >> 6;                 // wave id 0..7
    const int g0 = blockIdx.x * GPB;

    // zero the fp32 accumulator (4096 floats = 1024 float4)
    float4* u_s4z = reinterpret_cast<float4*>(u_s);
    u_s4z[t]       = make_float4(0.f, 0.f, 0.f, 0.f);
    u_s4z[t + 512] = make_float4(0.f, 0.f, 0.f, 0.f);
    if (t < GPB + 1) offs_s[t] = offs[g0 + t];

    // ---- B-fragments: W1 cols [w*32, w*32+32), bf16, registers ----
    // frag[ct][kt]: lane l holds B[k = kt*32+(l>>4)*8+j][col = w*32+ct*16+(l&15)]
    short8 bfrag[2][4];
    {
        const int lcol = w * 32 + (l & 15);
        #pragma unroll
        for (int ct = 0; ct < 2; ++ct) {
            const int col = lcol + ct * 16;
            #pragma unroll
            for (int kt = 0; kt < 4; ++kt) {
                const int k0 = kt * 32 + (l >> 4) * 8;
                short8 f;
                #pragma unroll
                for (int j = 0; j < 8; ++j)
                    f[j] = (short)f2bf(W1[(size_t)(k0 + j) * 256 + col]);
                bfrag[ct][kt] = f;
            }
        }
    }
    __syncthreads();   // u_s zeroed + offs_s ready

    // ---------------- Phase 1: block-interleaved segment-sum ----------------
    const float4* __restrict__ v4 = reinterpret_cast<const float4*>(v);
    const int blo = offs_s[0];
    const int bhi = offs_s[GPB];
    const int ri  = t >> 5;                // row slot 0..15 within a 16-row step
    const int qd  = t & 31;                // float4 quad within the row
    const int q4  = qd * 4;                // element offset

    const int r0 = blo + ri;
    const bool active = (r0 < bhi);
    int cur = 0, bnd = 0;
    float4 acc4 = make_float4(0.f, 0.f, 0.f, 0.f);
    if (active) {
        // largest cur in [0,31] with offs_s[cur] <= r0 (5-step LDS search)
        #pragma unroll
        for (int step = 16; step >= 1; step >>= 1)
            if (cur + step <= 31 && offs_s[cur + step] <= r0) cur += step;
        bnd = offs_s[cur + 1];
    }

    for (int base = blo; base < bhi; base += 64) {
        float4 x[4];
        #pragma unroll
        for (int i = 0; i < 4; ++i) {
            int rr = base + i * 16 + ri;
            rr = (rr < bhi) ? rr : (bhi - 1);        // clamp (masked below)
            x[i] = v4[(size_t)rr * 32 + qd];
        }
        #pragma unroll
        for (int i = 0; i < 4; ++i) {
            const int rr = base + i * 16 + ri;
            if (rr < bhi) {
                while (rr >= bnd) {                  // boundary: flush run
                    atomicAdd(&u_s[cur * HIDDEN + q4 + 0], acc4.x);
                    atomicAdd(&u_s[cur * HIDDEN + q4 + 1], acc4.y);
                    atomicAdd(&u_s[cur * HIDDEN + q4 + 2], acc4.z);
                    atomicAdd(&u_s[cur * HIDDEN + q4 + 3], acc4.w);
                    acc4 = make_float4(0.f, 0.f, 0.f, 0.f);
                    ++cur;                           // cur <= 31
                    bnd = offs_s[cur + 1];
                }
                acc4.x += x[i].x; acc4.y += x[i].y;
                acc4.z += x[i].z; acc4.w += x[i].w;
            }
        }
    }
    if (active) {                                    // final flush
        atomicAdd(&u_s[cur * HIDDEN + q4 + 0], acc4.x);
        atomicAdd(&u_s[cur * HIDDEN + q4 + 1], acc4.y);
        atomicAdd(&u_s[cur * HIDDEN + q4 + 2], acc4.z);
        atomicAdd(&u_s[cur * HIDDEN + q4 + 3], acc4.w);
    }
    __syncthreads();

    // ---------------- convert u_s fp32 -> u_b bf16 (swizzled) ----------------
    {
        const int row = t >> 4;                      // 0..31
        const int e0  = (t & 15) * 8;                // 0..120
        const float4 lo4 = *reinterpret_cast<const float4*>(&u_s[row * HIDDEN + e0]);
        const float4 hi4 = *reinterpret_cast<const float4*>(&u_s[row * HIDDEN + e0 + 4]);
        short8 pk;
        pk[0] = (short)f2bf(lo4.x); pk[1] = (short)f2bf(lo4.y);
        pk[2] = (short)f2bf(lo4.z); pk[3] = (short)f2bf(lo4.w);
        pk[4] = (short)f2bf(hi4.x); pk[5] = (short)f2bf(hi4.y);
        pk[6] = (short)f2bf(hi4.z); pk[7] = (short)f2bf(hi4.w);
        *reinterpret_cast<short8*>(&u_b[row * HIDDEN + (e0 ^ ((row & 7) * 8))]) = pk;
    }
    __syncthreads();

    // ---------------- Phase 2: MFMA MLP (unchanged from R8) ----------------
    f32x4 acc[2][2];                       // [row-tile][col-tile]
    #pragma unroll
    for (int rt = 0; rt < 2; ++rt)
        #pragma unroll
        for (int ct = 0; ct < 2; ++ct)
            acc[rt][ct] = (f32x4){0.f, 0.f, 0.f, 0.f};

    #pragma unroll
    for (int kt = 0; kt < 4; ++kt) {
        #pragma unroll
        for (int rt = 0; rt < 2; ++rt) {
            const int row = rt * 16 + (l & 15);
            const int k0  = kt * 32 + (l >> 4) * 8;
            short8 a = *reinterpret_cast<const short8*>(
                &u_b[row * HIDDEN + (k0 ^ ((row & 7) * 8))]);
            #pragma unroll
            for (int ct = 0; ct < 2; ++ct)
                acc[rt][ct] = __builtin_amdgcn_mfma_f32_16x16x32_bf16(
                    a, bfrag[ct][kt], acc[rt][ct], 0, 0, 0);
        }
    }

    // epilogue: bias -> shifted softplus -> *W2 -> reduce 16 cols -> LDS
    float b1c[2], w2c[2];
    #pragma unroll
    for (int ct = 0; ct < 2; ++ct) {
        const int col = w * 32 + ct * 16 + (l & 15);
        b1c[ct] = b1[col];
        w2c[ct] = W2[col];
    }
    #pragma unroll
    for (int rt = 0; rt < 2; ++rt) {
        float p[4] = {0.f, 0.f, 0.f, 0.f};
        #pragma unroll
        for (int ct = 0; ct < 2; ++ct)
            #pragma unroll
            for (int reg = 0; reg < 4; ++reg) {
                float x = acc[rt][ct][reg] + b1c[ct];
                float h = fmaxf(x, 0.f) + log1pf(expf(-fabsf(x))) - kSHIFT;
                p[reg] = fmaf(h, w2c[ct], p[reg]);
            }
        #pragma unroll
        for (int reg = 0; reg < 4; ++reg) {
            float s = p[reg];
            s += __shfl_xor(s, 1);
            s += __shfl_xor(s, 2);
            s += __shfl_xor(s, 4);
            s += __shfl_xor(s, 8);
            if ((l & 15) == 0)
                red_s[w][rt * 16 + (l >> 4) * 4 + reg] = s;
        }
    }
    __syncthreads();

    if (t < GPB) {
        float s = (red_s[0][t] + red_s[1][t]) + (red_s[2][t] + red_s[3][t])
                + (red_s[4][t] + red_s[5][t]) + (red_s[6][t] + red_s[7][t]);
        out[g0 + t] = s + b2[0];
    }
}

extern "C" void kernel_launch(void* const* d_in, const int* in_sizes, int n_in,
                              void* d_out, int out_size, void* d_ws, size_t ws_size,
                              hipStream_t stream) {
    const float* v     = (const float*)d_in[0];
    const int*   batch = (const int*)d_in[1];
    const float* W1    = (const float*)d_in[2];
    const float* b1    = (const float*)d_in[3];
    const float* W2    = (const float*)d_in[4];
    const float* b2    = (const float*)d_in[5];
    float* out = (float*)d_out;

    const int n_nodes = in_sizes[0] / HIDDEN;   // 500000
    int* offs = (int*)d_ws;                     // (NGRAPH+1) ints

    offsets_kernel<<<(n_nodes + 255) / 256, 256, 0, stream>>>(batch, offs, n_nodes);
    fused_kernel<<<NBLK, NTHR, 0, stream>>>(v, offs, W1, b1, W2, b2, out);
}

// Round 12
// 67.770 us; speedup vs baseline: 2.8010x; 2.8010x over previous
//
#include <hip/hip_runtime.h>
#include <math.h>

#define HIDDEN 128
#define NGRAPH 16384
#define GPB 32                  // graphs per block
#define NBLK (NGRAPH / GPB)     // 512 blocks
#define NTHR 512                // 8 waves/block; 2 blocks/CU = 16 waves/CU
#define WMARG 4096              // window margin (~11.6 sigma of boundary jitter)

typedef __attribute__((ext_vector_type(8))) short short8;   // 8 bf16
typedef __attribute__((ext_vector_type(4))) float f32x4;    // MFMA accum

// shifted-softplus shift = log(2)
__device__ __constant__ float kSHIFT = 0.69314718055994530942f;

// fp32 -> bf16 (RNE), bit-level
__device__ __forceinline__ unsigned short f2bf(float f) {
    unsigned int u = __builtin_bit_cast(unsigned int, f);
    u = (u + 0x7FFFu + ((u >> 16) & 1u)) >> 16;
    return (unsigned short)u;
}

// ---------------------------------------------------------------------------
// Single fused kernel (R8 structure + in-kernel PARALLEL offsets):
// 512 blocks x 512 threads (8 waves), 32 graphs/block.
// - Offsets via window scan: boundaries deviate from the linear estimate by
//   sigma ~354 rows, so batch[est(g0)-4096, est(g0+32)+4096) (~37 KB,
//   coalesced, L2/L3-hot) provably contains all 33 boundaries. 512 threads
//   scan ~18 ints each and write offs_s directly; binary-search fallback for
//   any entry not found (never taken in practice; covers offs[NGRAPH]).
//   Replaces the offsets kernel AND R9's serial per-wave search.
// - B-frags: W1 cols [w*32,w*32+32) loaded once into registers as bf16
//   (issued first; latency hides under the window scan).
// - Phase 1 (R8): each wave streams its 4 graphs' contiguous rows; 64 lanes
//   cover a row as float2; 8 rows per straight-line load block; wave-uniform
//   boundary flushes store bf16 XOR-swizzled rows into u_b.
// - Phase 2 (R8): 16 x v_mfma_f32_16x16x32_bf16 per wave, conflict-free
//   swizzled ds_read_b128 A-frags. Epilogue: bias -> shifted softplus ->
//   *W2 -> 16-lane shfl reduce -> cross-wave LDS reduce.
// LDS: 8 KB u_b + 1 KB red + 132 B offs ≈ 9.2 KB.
// ---------------------------------------------------------------------------
__global__ __launch_bounds__(NTHR, 4) void fused_kernel(
    const float* __restrict__ v, const int* __restrict__ batch,
    const float* __restrict__ W1, const float* __restrict__ b1,
    const float* __restrict__ W2, const float* __restrict__ b2,
    float* __restrict__ out, int n_nodes)
{
    __shared__ short u_b[GPB * HIDDEN];    // 8 KB, bf16, k XOR-swizzled per row
    __shared__ float red_s[8][GPB];        // 1 KB
    __shared__ int   offs_s[GPB + 1];

    const int t  = threadIdx.x;
    const int l  = t & 63;
    const int w  = t >> 6;                 // wave id 0..7
    const int g0 = blockIdx.x * GPB;

    if (t < GPB + 1) offs_s[t] = -1;

    // ---- B-fragments: W1 cols [w*32, w*32+32), bf16, registers ----
    // frag[ct][kt]: lane l holds B[k = kt*32+(l>>4)*8+j][col = w*32+ct*16+(l&15)]
    short8 bfrag[2][4];
    {
        const int lcol = w * 32 + (l & 15);
        #pragma unroll
        for (int ct = 0; ct < 2; ++ct) {
            const int col = lcol + ct * 16;
            #pragma unroll
            for (int kt = 0; kt < 4; ++kt) {
                const int k0 = kt * 32 + (l >> 4) * 8;
                short8 f;
                #pragma unroll
                for (int j = 0; j < 8; ++j)
                    f[j] = (short)f2bf(W1[(size_t)(k0 + j) * 256 + col]);
                bfrag[ct][kt] = f;
            }
        }
    }
    __syncthreads();   // offs_s init visible

    // ---- parallel window scan for the block's 33 offsets ----
    {
        const long long nn = n_nodes;
        const int est0  = (int)(nn * g0 / NGRAPH);
        const int est32 = (int)(nn * (g0 + GPB) / NGRAPH);
        const int wlo = max(0, est0 - WMARG);
        const int whi = min(n_nodes, est32 + WMARG);
        const int cnt = whi - wlo;
        const int ck  = (cnt + NTHR - 1) / NTHR;
        const int i0  = wlo + t * ck;
        const int i1  = min(i0 + ck, whi);
        for (int i = i0; i < i1; ++i) {
            const int b    = batch[i];
            const int prev = (i == 0) ? -1 : batch[i - 1];
            for (int g = prev + 1; g <= b; ++g) {         // usually 0-1 iters
                const int gl = g - g0;
                if (0 <= gl && gl <= GPB) offs_s[gl] = i;
            }
        }
        __syncthreads();
        // fallback: any entry not found (window miss / array end) -> lower_bound
        if (t <= GPB && offs_s[t] < 0) {
            const int target = g0 + t;
            int slo = 0, shi = n_nodes;
            while (slo < shi) {
                int mid = (slo + shi) >> 1;
                if (batch[mid] < target) slo = mid + 1; else shi = mid;
            }
            offs_s[t] = slo;
        }
        __syncthreads();
    }

    // ---------------- Phase 1: continuous segment-sum stream ----------------
    const float2* __restrict__ v2 = reinterpret_cast<const float2*>(v);
    const int w4 = w * 4;                  // this wave's first local graph
    const int lo = offs_s[w4];
    const int hi = offs_s[w4 + 4];
    int cur = 0;
    int bnd = offs_s[w4 + 1];
    float accx = 0.f, accy = 0.f;
    const int k2 = 2 * l;                  // lane's k-pair base

    for (int r = lo; r < hi; r += 8) {
        float2 x[8];
        #pragma unroll
        for (int q = 0; q < 8; ++q) {
            int rq = r + q;
            rq = (rq < hi) ? rq : (hi - 1);          // clamp tail (uniform)
            x[q] = v2[(size_t)rq * 64 + l];
        }
        #pragma unroll
        for (int q = 0; q < 8; ++q) {
            if (r + q < hi) {
                while (r + q >= bnd) {               // taken ~1 in 30 rows
                    const int row = w4 + cur;
                    const int idx = row * HIDDEN + (k2 ^ ((row & 7) * 8));
                    unsigned int pk = (unsigned int)f2bf(accx)
                                    | ((unsigned int)f2bf(accy) << 16);
                    *reinterpret_cast<unsigned int*>(&u_b[idx]) = pk;
                    accx = 0.f; accy = 0.f;
                    ++cur;
                    bnd = offs_s[w4 + cur + 1];      // index <= 32
                }
                accx += x[q].x; accy += x[q].y;
            }
        }
    }
    while (cur < 4) {                                 // flush last + empties
        const int row = w4 + cur;
        const int idx = row * HIDDEN + (k2 ^ ((row & 7) * 8));
        unsigned int pk = (unsigned int)f2bf(accx)
                        | ((unsigned int)f2bf(accy) << 16);
        *reinterpret_cast<unsigned int*>(&u_b[idx]) = pk;
        accx = 0.f; accy = 0.f;
        ++cur;
    }
    __syncthreads();

    // ---------------- Phase 2: MFMA MLP ----------------
    f32x4 acc[2][2];                       // [row-tile][col-tile]
    #pragma unroll
    for (int rt = 0; rt < 2; ++rt)
        #pragma unroll
        for (int ct = 0; ct < 2; ++ct)
            acc[rt][ct] = (f32x4){0.f, 0.f, 0.f, 0.f};

    #pragma unroll
    for (int kt = 0; kt < 4; ++kt) {
        #pragma unroll
        for (int rt = 0; rt < 2; ++rt) {
            const int row = rt * 16 + (l & 15);
            const int k0  = kt * 32 + (l >> 4) * 8;
            short8 a = *reinterpret_cast<const short8*>(
                &u_b[row * HIDDEN + (k0 ^ ((row & 7) * 8))]);
            #pragma unroll
            for (int ct = 0; ct < 2; ++ct)
                acc[rt][ct] = __builtin_amdgcn_mfma_f32_16x16x32_bf16(
                    a, bfrag[ct][kt], acc[rt][ct], 0, 0, 0);
        }
    }

    // epilogue: bias -> shifted softplus -> *W2 -> reduce 16 cols -> LDS
    float b1c[2], w2c[2];
    #pragma unroll
    for (int ct = 0; ct < 2; ++ct) {
        const int col = w * 32 + ct * 16 + (l & 15);
        b1c[ct] = b1[col];
        w2c[ct] = W2[col];
    }
    #pragma unroll
    for (int rt = 0; rt < 2; ++rt) {
        float p[4] = {0.f, 0.f, 0.f, 0.f};
        #pragma unroll
        for (int ct = 0; ct < 2; ++ct)
            #pragma unroll
            for (int reg = 0; reg < 4; ++reg) {
                float x = acc[rt][ct][reg] + b1c[ct];
                float h = fmaxf(x, 0.f) + log1pf(expf(-fabsf(x))) - kSHIFT;
                p[reg] = fmaf(h, w2c[ct], p[reg]);
            }
        #pragma unroll
        for (int reg = 0; reg < 4; ++reg) {
            float s = p[reg];
            s += __shfl_xor(s, 1);
            s += __shfl_xor(s, 2);
            s += __shfl_xor(s, 4);
            s += __shfl_xor(s, 8);
            if ((l & 15) == 0)
                red_s[w][rt * 16 + (l >> 4) * 4 + reg] = s;
        }
    }
    __syncthreads();

    if (t < GPB) {
        float s = (red_s[0][t] + red_s[1][t]) + (red_s[2][t] + red_s[3][t])
                + (red_s[4][t] + red_s[5][t]) + (red_s[6][t] + red_s[7][t]);
        out[g0 + t] = s + b2[0];
    }
}

extern "C" void kernel_launch(void* const* d_in, const int* in_sizes, int n_in,
                              void* d_out, int out_size, void* d_ws, size_t ws_size,
                              hipStream_t stream) {
    const float* v     = (const float*)d_in[0];
    const int*   batch = (const int*)d_in[1];
    const float* W1    = (const float*)d_in[2];
    const float* b1    = (const float*)d_in[3];
    const float* W2    = (const float*)d_in[4];
    const float* b2    = (const float*)d_in[5];
    float* out = (float*)d_out;

    const int n_nodes = in_sizes[0] / HIDDEN;   // 500000

    fused_kernel<<<NBLK, NTHR, 0, stream>>>(v, batch, W1, b1, W2, b2, out, n_nodes);
}

// Round 13
// 62.834 us; speedup vs baseline: 3.0210x; 1.0786x over previous
//
#include <hip/hip_runtime.h>
#include <math.h>

#define HIDDEN 128
#define NGRAPH 16384
#define GPB 32                  // graphs per block
#define NBLK (NGRAPH / GPB)     // 512 blocks
#define NTHR 512                // 8 waves/block; 2 blocks/CU = 16 waves/CU

typedef __attribute__((ext_vector_type(8))) short short8;   // 8 bf16
typedef __attribute__((ext_vector_type(4))) float f32x4;    // MFMA accum

// shifted-softplus shift = log(2)
__device__ __constant__ float kSHIFT = 0.69314718055994530942f;

// fp32 -> bf16 (RNE), bit-level
__device__ __forceinline__ unsigned short f2bf(float f) {
    unsigned int u = __builtin_bit_cast(unsigned int, f);
    u = (u + 0x7FFFu + ((u >> 16) & 1u)) >> 16;
    return (unsigned short)u;
}

// ---------------------------------------------------------------------------
// Kernel 0: boundary scan. batch sorted; thread i writes offs[g]=i for every
// graph g starting at i (covers empty graphs). offs[NGRAPH]=n_nodes.
// (R9/R12 showed in-kernel offset computation costs the same or more --
//  the separate kernel amortizes it chip-wide. Keep it.)
// ---------------------------------------------------------------------------
__global__ __launch_bounds__(256) void offsets_kernel(
    const int* __restrict__ batch, int* __restrict__ offs, int n_nodes)
{
    int i = blockIdx.x * blockDim.x + threadIdx.x;
    if (i >= n_nodes) return;
    int b = batch[i];
    int prev = (i == 0) ? -1 : batch[i - 1];
    for (int g = prev + 1; g <= b; ++g) offs[g] = i;        // rare
    if (i == n_nodes - 1)
        for (int g = b + 1; g <= NGRAPH; ++g) offs[g] = n_nodes;
}

// ---------------------------------------------------------------------------
// Fused kernel: 512 blocks x 512 threads (8 waves), 32 graphs/block.
// Phase 1 (WIDENED vs R8): each wave streams its 4 graphs' contiguous rows
//   with float4 loads (16 B/lane): lane = quad (l&31) of row-parity (l>>5).
//   16 rows per straight-line block = 8 loads in flight/lane = 8 KB/wave
//   (128 KB/CU in flight; halves load-instruction count vs R8's float2).
//   Graph-boundary walk is ROW-uniform across the wave, so the rare flush
//   (combine parities via shfl_xor(32), lane-half 0 stores bf16 short4
//   XOR-swizzled into u_b) never diverges.
// B-frags (MOVED vs R8): W1 cols [w*32,w*32+32) loaded once into registers
//   AFTER the streaming loop -- early-finishing waves fetch them while
//   laggards still stream; phase-2 s_waitcnt pipelining absorbs the rest.
// Phase 2 (unchanged from R8): 16 x v_mfma_f32_16x16x32_bf16 per wave,
//   conflict-free swizzled ds_read_b128 A-frags. Epilogue: bias -> shifted
//   softplus -> *W2 -> 16-lane shfl reduce -> cross-wave LDS reduce.
// LDS: 8 KB u_b + 1 KB red + 132 B offs.
// ---------------------------------------------------------------------------
__global__ __launch_bounds__(NTHR, 4) void fused_kernel(
    const float* __restrict__ v, const int* __restrict__ offs,
    const float* __restrict__ W1, const float* __restrict__ b1,
    const float* __restrict__ W2, const float* __restrict__ b2,
    float* __restrict__ out)
{
    __shared__ short u_b[GPB * HIDDEN];    // 8 KB, bf16, k XOR-swizzled per row
    __shared__ float red_s[8][GPB];        // 1 KB
    __shared__ int   offs_s[GPB + 1];

    const int t  = threadIdx.x;
    const int l  = t & 63;
    const int w  = t >> 6;                 // wave id 0..7
    const int g0 = blockIdx.x * GPB;
    const int w4 = w * 4;                  // this wave's first local graph

    if (t < GPB + 1) offs_s[t] = offs[g0 + t];
    __syncthreads();

    // ---------------- Phase 1: continuous segment-sum stream ----------------
    const float4* __restrict__ v4 = reinterpret_cast<const float4*>(v);
    const int qd = l & 31;                 // float4 quad within the row
    const int ro = l >> 5;                 // row parity 0/1
    const int lo = offs_s[w4];
    const int hi = offs_s[w4 + 4];
    int cur = 0;
    int bnd = offs_s[w4 + 1];
    float4 a4 = make_float4(0.f, 0.f, 0.f, 0.f);

    for (int r = lo; r < hi; r += 16) {
        // straight-line load block: 8 float4 loads in flight per lane
        float4 x[8];
        #pragma unroll
        for (int jj = 0; jj < 8; ++jj) {
            int rq = r + 2 * jj + ro;
            rq = (rq < hi) ? rq : (hi - 1);          // clamp tail
            x[jj] = v4[(size_t)rq * 32 + qd];
        }
        // row-uniform boundary walk; lane accumulates rows of its parity
        #pragma unroll
        for (int q = 0; q < 16; ++q) {
            const int row = r + q;
            if (row < hi) {
                while (row >= bnd) {                 // rare; wave-uniform
                    // combine parities and store graph (w4+cur) as bf16
                    float4 s;
                    s.x = a4.x + __shfl_xor(a4.x, 32);
                    s.y = a4.y + __shfl_xor(a4.y, 32);
                    s.z = a4.z + __shfl_xor(a4.z, 32);
                    s.w = a4.w + __shfl_xor(a4.w, 32);
                    if (ro == 0) {
                        const int urow = w4 + cur;
                        const int idx  = urow * HIDDEN + ((4 * qd) ^ ((urow & 7) * 8));
                        uint2 pk;
                        pk.x = (unsigned int)f2bf(s.x) | ((unsigned int)f2bf(s.y) << 16);
                        pk.y = (unsigned int)f2bf(s.z) | ((unsigned int)f2bf(s.w) << 16);
                        *reinterpret_cast<uint2*>(&u_b[idx]) = pk;
                    }
                    a4 = make_float4(0.f, 0.f, 0.f, 0.f);
                    ++cur;
                    bnd = offs_s[w4 + cur + 1];      // index <= 32
                }
                if ((q & 1) == ro) {
                    const float4 xx = x[q >> 1];
                    a4.x += xx.x; a4.y += xx.y; a4.z += xx.z; a4.w += xx.w;
                }
            }
        }
    }
    while (cur < 4) {                                 // flush last + empties
        float4 s;
        s.x = a4.x + __shfl_xor(a4.x, 32);
        s.y = a4.y + __shfl_xor(a4.y, 32);
        s.z = a4.z + __shfl_xor(a4.z, 32);
        s.w = a4.w + __shfl_xor(a4.w, 32);
        if (ro == 0) {
            const int urow = w4 + cur;
            const int idx  = urow * HIDDEN + ((4 * qd) ^ ((urow & 7) * 8));
            uint2 pk;
            pk.x = (unsigned int)f2bf(s.x) | ((unsigned int)f2bf(s.y) << 16);
            pk.y = (unsigned int)f2bf(s.z) | ((unsigned int)f2bf(s.w) << 16);
            *reinterpret_cast<uint2*>(&u_b[idx]) = pk;
        }
        a4 = make_float4(0.f, 0.f, 0.f, 0.f);
        ++cur;
    }

    // ---- B-fragments: W1 cols [w*32, w*32+32), bf16, registers ----
    // Loaded AFTER streaming so they don't collide with the load stream.
    // frag[ct][kt]: lane l holds B[k = kt*32+(l>>4)*8+j][col = w*32+ct*16+(l&15)]
    short8 bfrag[2][4];
    {
        const int lcol = w * 32 + (l & 15);
        #pragma unroll
        for (int ct = 0; ct < 2; ++ct) {
            const int col = lcol + ct * 16;
            #pragma unroll
            for (int kt = 0; kt < 4; ++kt) {
                const int k0 = kt * 32 + (l >> 4) * 8;
                short8 f;
                #pragma unroll
                for (int j = 0; j < 8; ++j)
                    f[j] = (short)f2bf(W1[(size_t)(k0 + j) * 256 + col]);
                bfrag[ct][kt] = f;
            }
        }
    }
    __syncthreads();

    // ---------------- Phase 2: MFMA MLP ----------------
    f32x4 acc[2][2];                       // [row-tile][col-tile]
    #pragma unroll
    for (int rt = 0; rt < 2; ++rt)
        #pragma unroll
        for (int ct = 0; ct < 2; ++ct)
            acc[rt][ct] = (f32x4){0.f, 0.f, 0.f, 0.f};

    #pragma unroll
    for (int kt = 0; kt < 4; ++kt) {
        #pragma unroll
        for (int rt = 0; rt < 2; ++rt) {
            const int row = rt * 16 + (l & 15);
            const int k0  = kt * 32 + (l >> 4) * 8;
            short8 a = *reinterpret_cast<const short8*>(
                &u_b[row * HIDDEN + (k0 ^ ((row & 7) * 8))]);
            #pragma unroll
            for (int ct = 0; ct < 2; ++ct)
                acc[rt][ct] = __builtin_amdgcn_mfma_f32_16x16x32_bf16(
                    a, bfrag[ct][kt], acc[rt][ct], 0, 0, 0);
        }
    }

    // epilogue: bias -> shifted softplus -> *W2 -> reduce 16 cols -> LDS
    float b1c[2], w2c[2];
    #pragma unroll
    for (int ct = 0; ct < 2; ++ct) {
        const int col = w * 32 + ct * 16 + (l & 15);
        b1c[ct] = b1[col];
        w2c[ct] = W2[col];
    }
    #pragma unroll
    for (int rt = 0; rt < 2; ++rt) {
        float p[4] = {0.f, 0.f, 0.f, 0.f};
        #pragma unroll
        for (int ct = 0; ct < 2; ++ct)
            #pragma unroll
            for (int reg = 0; reg < 4; ++reg) {
                float x = acc[rt][ct][reg] + b1c[ct];
                float h = fmaxf(x, 0.f) + log1pf(expf(-fabsf(x))) - kSHIFT;
                p[reg] = fmaf(h, w2c[ct], p[reg]);
            }
        #pragma unroll
        for (int reg = 0; reg < 4; ++reg) {
            float s = p[reg];
            s += __shfl_xor(s, 1);
            s += __shfl_xor(s, 2);
            s += __shfl_xor(s, 4);
            s += __shfl_xor(s, 8);
            if ((l & 15) == 0)
                red_s[w][rt * 16 + (l >> 4) * 4 + reg] = s;
        }
    }
    __syncthreads();

    if (t < GPB) {
        float s = (red_s[0][t] + red_s[1][t]) + (red_s[2][t] + red_s[3][t])
                + (red_s[4][t] + red_s[5][t]) + (red_s[6][t] + red_s[7][t]);
        out[g0 + t] = s + b2[0];
    }
}

extern "C" void kernel_launch(void* const* d_in, const int* in_sizes, int n_in,
                              void* d_out, int out_size, void* d_ws, size_t ws_size,
                              hipStream_t stream) {
    const float* v     = (const float*)d_in[0];
    const int*   batch = (const int*)d_in[1];
    const float* W1    = (const float*)d_in[2];
    const float* b1    = (const float*)d_in[3];
    const float* W2    = (const float*)d_in[4];
    const float* b2    = (const float*)d_in[5];
    float* out = (float*)d_out;

    const int n_nodes = in_sizes[0] / HIDDEN;   // 500000
    int* offs = (int*)d_ws;                     // (NGRAPH+1) ints

    offsets_kernel<<<(n_nodes + 255) / 256, 256, 0, stream>>>(batch, offs, n_nodes);
    fused_kernel<<<NBLK, NTHR, 0, stream>>>(v, offs, W1, b1, W2, b2, out);
}